// Round 15
// baseline (100.885 us; speedup 1.0000x reference)
//
#include <hip/hip_runtime.h>

typedef unsigned short u16;
typedef unsigned int   u32;
typedef __bf16 bf16x8 __attribute__((ext_vector_type(8)));
typedef float  f32x4  __attribute__((ext_vector_type(4)));

#define B_DIM 2
#define T_DIM 2048
#define C_DIM 768
#define H_DIM 12
#define D_DIM 64
#define KD 768  // GEMM K dim (= C)

__device__ __forceinline__ u16 f2bf(float f) {
    union { float f; u32 u; } v; v.f = f;
    u32 r = v.u + 0x7FFFu + ((v.u >> 16) & 1u);   // RNE
    return (u16)(r >> 16);
}

__device__ __forceinline__ u32 cvt_pk_bf16(float lo, float hi) {
    u32 r;
    asm("v_cvt_pk_bf16_f32 %0, %1, %2" : "=v"(r) : "v"(lo), "v"(hi));
    return r;
}

__device__ __forceinline__ float exp2_hw(float x) {
    float r;
    asm("v_exp_f32 %0, %1" : "=v"(r) : "v"(x));
    return r;
}

__device__ __forceinline__ void load_lds16(const void* g, void* l) {
    __builtin_amdgcn_global_load_lds(
        (const __attribute__((address_space(1))) u32*)g,
        (__attribute__((address_space(3))) u32*)l,
        16, 0, 0);
}

// ---------------- fused prep: x fp32->bf16  +  W_attn / W_proj transpose+convert ----------------
__global__ __launch_bounds__(256)
void prep(const float* __restrict__ x,      u16* __restrict__ xb,
          const float* __restrict__ WA,     u16* __restrict__ WtA,
          const float* __restrict__ WP,     u16* __restrict__ WtP) {
    const int bid = blockIdx.x;
    const int tid = threadIdx.x;
    if (bid < 3072) {
        int i = bid * 256 + tid;
        float4 v = ((const float4*)x)[i];
        ushort4 o;
        o.x = f2bf(v.x); o.y = f2bf(v.y); o.z = f2bf(v.z); o.w = f2bf(v.w);
        ((ushort4*)xb)[i] = o;
        return;
    }
    __shared__ float tile[32][33];
    const float* W; u16* Wt; int N, idx;
    if (bid < 4800) { W = WA; Wt = WtA; N = 2304; idx = bid - 3072; }
    else            { W = WP; Wt = WtP; N = 768;  idx = bid - 4800; }
    const int tilesx = N / 32;
    const int bx = (idx % tilesx) * 32, by = (idx / tilesx) * 32;
    const int tx = tid & 31, ty = tid >> 5;
#pragma unroll
    for (int i = ty; i < 32; i += 8) tile[i][tx] = W[(size_t)(by + i) * N + bx + tx];
    __syncthreads();
#pragma unroll
    for (int i = ty; i < 32; i += 8) Wt[(size_t)(bx + i) * KD + by + tx] = f2bf(tile[tx][i]);
}

// ---------------- GEMM: A[M][768] bf16 @ Bt[N][768]^T, 128 x (NJ*32) tile, BK=64 ----------------
// T2 XOR-swizzle, double-buffered LDS with counted vmcnt(4+NJ), setprio on MFMA cluster.
// NJ=4 (QKV): 4x4 acc/wave -> 32 MFMA per 16 ds_read_b128 (2x arithmetic intensity vs NJ=2;
// m93/m97 verified 128^2 geometry).  NJ=2 (proj): keeps block count at skinny N.
template <int EPI, int NJ>
__global__ __launch_bounds__(256)
void gemm_bt(const u16* __restrict__ A, const u16* __restrict__ Bt,
             const float* __restrict__ bias,
             u16* __restrict__ Qb, u16* __restrict__ Kb, u16* __restrict__ Vt,
             float* __restrict__ Cout) {
    __shared__ u16 lA[2][128 * 64];
    __shared__ u16 lB[2][NJ * 32 * 64];
    const int tid  = threadIdx.x;
    const int lane = tid & 63, wv = tid >> 6;
    const int lr = lane & 15, lg = lane >> 4;
    const int wm = wv >> 1, wn = wv & 1;
    const int sw = (lr & 7) << 3;                         // read-side XOR (elem units)
    const int scol = (((lane & 7) ^ (lane >> 3)) << 3);   // pre-swizzled source col (elems)
    const int row0 = blockIdx.y * 128, col0 = blockIdx.x * (NJ * 32);

    const f32x4 Z4 = {0.f, 0.f, 0.f, 0.f};
    f32x4 acc[4][NJ];
#pragma unroll
    for (int i = 0; i < 4; i++)
#pragma unroll
        for (int j = 0; j < NJ; j++) acc[i][j] = Z4;

    auto stage = [&](int p, int kt) {
#pragma unroll
        for (int i = 0; i < 4; i++) {               // A: 16 chunks of 1KB
            int chunk = wv * 4 + i;
            int row = chunk * 8 + (lane >> 3);
            load_lds16(&A[(size_t)(row0 + row) * KD + kt * 64 + scol], &lA[p][chunk * 512]);
        }
#pragma unroll
        for (int i = 0; i < NJ; i++) {              // B: NJ*4 chunks of 1KB
            int chunk = wv * NJ + i;
            int row = chunk * 8 + (lane >> 3);
            load_lds16(&Bt[(size_t)(col0 + row) * KD + kt * 64 + scol], &lB[p][chunk * 512]);
        }
    };

    auto compute = [&](int p) {
#pragma unroll
        for (int kk = 0; kk < 2; kk++) {
            bf16x8 af[4], bfr[NJ];
#pragma unroll
            for (int i = 0; i < 4; i++)
                af[i] = *(const bf16x8*)&lA[p][(wm * 64 + i * 16 + lr) * 64 + ((kk * 32 + lg * 8) ^ sw)];
#pragma unroll
            for (int j = 0; j < NJ; j++)
                bfr[j] = *(const bf16x8*)&lB[p][(wn * (NJ * 16) + j * 16 + lr) * 64 + ((kk * 32 + lg * 8) ^ sw)];
            __builtin_amdgcn_s_setprio(1);
#pragma unroll
            for (int i = 0; i < 4; i++)
#pragma unroll
                for (int j = 0; j < NJ; j++)
                    acc[i][j] = __builtin_amdgcn_mfma_f32_16x16x32_bf16(af[i], bfr[j], acc[i][j], 0, 0, 0);
            __builtin_amdgcn_s_setprio(0);
        }
    };

    stage(0, 0);
    for (int kt = 0; kt < KD / 64; ++kt) {
        const int p = kt & 1;
        if (kt + 1 < KD / 64) {
            stage(p ^ 1, kt + 1);
            // wait until only next tile's (4+NJ) loads remain in flight
            if constexpr (NJ == 4) asm volatile("s_waitcnt vmcnt(8)" ::: "memory");
            else                   asm volatile("s_waitcnt vmcnt(6)" ::: "memory");
        } else {
            asm volatile("s_waitcnt vmcnt(0)" ::: "memory");
        }
        __builtin_amdgcn_sched_barrier(0);
        __builtin_amdgcn_s_barrier();
        __builtin_amdgcn_sched_barrier(0);
        compute(p);
        __builtin_amdgcn_sched_barrier(0);
        __builtin_amdgcn_s_barrier();
    }

    if (EPI == 0) {
        const int b  = row0 >> 11;
        const int t0 = (row0 & 2047) + wm * 64;
        const float qscale = 0.125f * 1.44269504088896340736f;  // fold log2(e)
#pragma unroll
        for (int i = 0; i < 4; i++) {
#pragma unroll
            for (int j = 0; j < NJ; j++) {
                const int n   = col0 + wn * (NJ * 16) + j * 16 + lr;
                const int seg = n / 768;
                const int nn  = n - seg * 768;
                const int h   = nn >> 6;
                const int d   = nn & 63;
                const float bv = bias[n];
                const int tb  = t0 + i * 16 + lg * 4;
                if (seg == 2) {
                    // Vt rows contiguous in t: pack 4 consecutive t into one 8B store
                    u32 w0 = cvt_pk_bf16(acc[i][j][0] + bv, acc[i][j][1] + bv);
                    u32 w1 = cvt_pk_bf16(acc[i][j][2] + bv, acc[i][j][3] + bv);
                    uint2 dw; dw.x = w0; dw.y = w1;
                    *(uint2*)&Vt[((size_t)(b * H_DIM + h) * D_DIM + d) * T_DIM + tb] = dw;
                } else if (seg == 0) {
#pragma unroll
                    for (int r = 0; r < 4; r++)
                        Qb[((size_t)(b * H_DIM + h) * T_DIM + tb + r) * D_DIM + d] =
                            f2bf((acc[i][j][r] + bv) * qscale);
                } else {
#pragma unroll
                    for (int r = 0; r < 4; r++)
                        Kb[((size_t)(b * H_DIM + h) * T_DIM + tb + r) * D_DIM + d] =
                            f2bf(acc[i][j][r] + bv);
                }
            }
        }
    } else {
#pragma unroll
        for (int i = 0; i < 4; i++)
#pragma unroll
            for (int j = 0; j < NJ; j++) {
                const int n  = col0 + wn * (NJ * 16) + j * 16 + lr;
                const float bv = bias[n];
#pragma unroll
                for (int r = 0; r < 4; r++) {
                    const int m = row0 + wm * 64 + i * 16 + lg * 4 + r;
                    Cout[(size_t)m * 768 + n] = acc[i][j][r] + bv;
                }
            }
    }
}

// ---------------- causal flash attention: 4-wave LDS-staged blocks + split-K ----------------
// Work item = (bh, 128-row q-chunk c, <=512-key segment s).  40 items/bh, 960 blocks.
// 2-buffer LDS, 1-deep prefetch, counted vmcnt(4), XOR swizzle, in-register softmax/PV.
// (R14's fused last-block merge REVERTED: cross-block acquire pairing failed on-device.)
union VFrag  { struct { ushort4 lo, hi; } s; bf16x8 v; };
union PFrag  { u32 w[4]; bf16x8 v; };
union QU     { f32x4 f; bf16x8 b; };

#define NPSEG 36   // partial-segment slots per bh (chunks c>=4)

__global__ __launch_bounds__(256)
void attn_kernel(const u16* __restrict__ Qb, const u16* __restrict__ Kb,
                 const u16* __restrict__ Vt, u16* __restrict__ Yb,
                 u16* __restrict__ Yp, float2* __restrict__ Ml) {
    __shared__ u16 ldsK[2][64 * 64];
    __shared__ u16 ldsV[2][64 * 64];

    const int i    = blockIdx.x;
    const int bh   = (i & 7) + 8 * ((i >> 3) % 3);
    const int rank = (i >> 3) / 3;              // 0..39
    int c, s;
    if (rank < 4)       { c = 4 + rank;              s = 0; }
    else if (rank < 12) { c = 8 + ((rank - 4) >> 1); s = (rank - 4) & 1; }
    else if (rank < 24) { c = 12 + (rank - 12) / 3;  s = (rank - 12) % 3; }
    else { int j = rank - 24; c = 4 * (j & 3) + (3 - (j >> 2)); s = c >> 2; }
    const int nseg = (c >> 2) + 1;

    const int b = bh / H_DIM, h = bh % H_DIM;
    const int tid  = threadIdx.x;
    const int lane = tid & 63, wv = tid >> 6;
    const int lr = lane & 15, lg = lane >> 4;
    const int sw = (lr & 7) << 3;               // read-side XOR swizzle (elem units)
    const int q0 = c * 128;
    const int qbase = q0 + wv * 32;
    const int my_kend = qbase + 32;
    const int k0 = s * 512;
    const int k1 = min(512 * (s + 1), q0 + 128);
    const int nt = (k1 - k0) >> 6;              // 2..8 tiles

    const u16* Qp = Qb + (size_t)bh * T_DIM * D_DIM;
    const u16* Kp = Kb + (size_t)bh * T_DIM * D_DIM;
    const u16* Vp = Vt + (size_t)bh * D_DIM * T_DIM;

    // Q fragments (B-operand): col = lr = q-within-16, contraction d = lg*8+j
    QU qf[2][2];
#pragma unroll
    for (int m = 0; m < 2; m++)
#pragma unroll
        for (int dh = 0; dh < 2; dh++)
            qf[m][dh].f = *(const f32x4*)&Qp[(size_t)(qbase + m * 16 + lr) * 64 + dh * 32 + lg * 8];
    asm volatile("" :: "v"(qf[0][0].f), "v"(qf[0][1].f), "v"(qf[1][0].f), "v"(qf[1][1].f));

    const f32x4 Z4 = {0.f, 0.f, 0.f, 0.f};
    f32x4 yacc[2][4];
    float mrun[2] = {-1e30f, -1e30f};
    float lrun[2] = {0.f, 0.f};
#pragma unroll
    for (int m = 0; m < 2; m++)
#pragma unroll
        for (int n = 0; n < 4; n++) yacc[m][n] = Z4;

    // staging geometry: wave w stages rows [16w,16w+16) of K and V (2 instrs each of 8 rows)
    const int srow = wv * 16 + (lane >> 3);
    const int scol = (((lane & 7) ^ (lane >> 3)) << 3);   // pre-swizzled source col (elems)

    auto stage = [&](int p, int kc) {
#pragma unroll
        for (int j = 0; j < 2; j++) {
            const int r = srow + j * 8;
            load_lds16(Kp + (size_t)(kc + r) * 64 + scol, &ldsK[p][(wv * 16 + j * 8) * 64]);
            load_lds16(Vp + (size_t)r * T_DIM + kc + scol, &ldsV[p][(wv * 16 + j * 8) * 64]);
        }
    };

    auto compute = [&](int p, int kc) {
        // ---- K frags from LDS (swizzled) ----
        QU k0f[4], k1f[4];
#pragma unroll
        for (int kf = 0; kf < 4; kf++) {
            const u16* krow = &ldsK[p][(kf * 16 + lr) * 64];
            k0f[kf].f = *(const f32x4*)&krow[(lg * 8) ^ sw];
            k1f[kf].f = *(const f32x4*)&krow[(32 + lg * 8) ^ sw];
        }
        // ---- S^T = K @ Q^T ----
        f32x4 S[2][4];
#pragma unroll
        for (int m = 0; m < 2; m++)
#pragma unroll
            for (int kf = 0; kf < 4; kf++) S[m][kf] = Z4;
        __builtin_amdgcn_s_setprio(1);
#pragma unroll
        for (int kf = 0; kf < 4; kf++)
#pragma unroll
            for (int m = 0; m < 2; m++) {
                S[m][kf] = __builtin_amdgcn_mfma_f32_16x16x32_bf16(k0f[kf].b, qf[m][0].b, S[m][kf], 0, 0, 0);
                S[m][kf] = __builtin_amdgcn_mfma_f32_16x16x32_bf16(k1f[kf].b, qf[m][1].b, S[m][kf], 0, 0, 0);
            }
        __builtin_amdgcn_s_setprio(0);

        // ---- causal mask (diagonal-crossing tiles only) ----
        if (kc + 63 > qbase) {
#pragma unroll
            for (int m = 0; m < 2; m++) {
                const int q = qbase + m * 16 + lr;
#pragma unroll
                for (int kf = 0; kf < 4; kf++)
#pragma unroll
                    for (int r = 0; r < 4; r++) {
                        const int k = kc + kf * 16 + 4 * lg + r;
                        if (k > q) S[m][kf][r] = -1e30f;
                    }
            }
        }

        // ---- online softmax with defer-max ----
        PFrag pf[2][2];
#pragma unroll
        for (int m = 0; m < 2; m++) {
            float mx = -1e30f;
#pragma unroll
            for (int kf = 0; kf < 4; kf++) {
                float a = fmaxf(S[m][kf][0], S[m][kf][1]);
                float cm = fmaxf(S[m][kf][2], S[m][kf][3]);
                mx = fmaxf(mx, fmaxf(a, cm));
            }
            mx = fmaxf(mx, __shfl_xor(mx, 16));
            mx = fmaxf(mx, __shfl_xor(mx, 32));
            if (!__all(mx <= mrun[m] + 8.0f)) {
                float mnew = fmaxf(mrun[m], mx);
                float sfr  = exp2_hw(mrun[m] - mnew);
                mrun[m] = mnew;
                lrun[m] *= sfr;
#pragma unroll
                for (int n = 0; n < 4; n++)
#pragma unroll
                    for (int r = 0; r < 4; r++) yacc[m][n][r] *= sfr;
            }
            float sum = 0.f;
#pragma unroll
            for (int kf = 0; kf < 4; kf++)
#pragma unroll
                for (int r = 0; r < 4; r++) {
                    float pb = exp2_hw(S[m][kf][r] - mrun[m]);
                    S[m][kf][r] = pb;
                    sum += pb;
                }
            sum += __shfl_xor(sum, 16);
            sum += __shfl_xor(sum, 32);
            lrun[m] += sum;
#pragma unroll
            for (int sv = 0; sv < 2; sv++) {
                pf[m][sv].w[0] = cvt_pk_bf16(S[m][2 * sv][0],     S[m][2 * sv][1]);
                pf[m][sv].w[1] = cvt_pk_bf16(S[m][2 * sv][2],     S[m][2 * sv][3]);
                pf[m][sv].w[2] = cvt_pk_bf16(S[m][2 * sv + 1][0], S[m][2 * sv + 1][1]);
                pf[m][sv].w[3] = cvt_pk_bf16(S[m][2 * sv + 1][2], S[m][2 * sv + 1][3]);
            }
        }

        // ---- y^T += V^T @ P^T  (V frags from LDS, swizzled; own-register P slots) ----
        __builtin_amdgcn_s_setprio(1);
#pragma unroll
        for (int sv = 0; sv < 2; sv++) {
            VFrag av[4];
#pragma unroll
            for (int n = 0; n < 4; n++) {
                const u16* vrow = &ldsV[p][(n * 16 + lr) * 64];
                av[n].s.lo = *(const ushort4*)&vrow[(sv * 32 + 4 * lg) ^ sw];
                av[n].s.hi = *(const ushort4*)&vrow[(sv * 32 + 16 + 4 * lg) ^ sw];
            }
#pragma unroll
            for (int n = 0; n < 4; n++)
#pragma unroll
                for (int m = 0; m < 2; m++)
                    yacc[m][n] = __builtin_amdgcn_mfma_f32_16x16x32_bf16(av[n].v, pf[m][sv].v, yacc[m][n], 0, 0, 0);
        }
        __builtin_amdgcn_s_setprio(0);
    };

    // ---- pipelined tile loop: stage(t+1) in flight across the barrier (counted vmcnt) ----
    stage(0, k0);
    for (int t = 0; t < nt; ++t) {
        const int p = t & 1;
        if (t + 1 < nt) {
            stage(p ^ 1, k0 + 64 * (t + 1));
            asm volatile("s_waitcnt vmcnt(4)" ::: "memory");   // tile t landed; t+1 in flight
        } else {
            asm volatile("s_waitcnt vmcnt(0)" ::: "memory");
        }
        __builtin_amdgcn_sched_barrier(0);
        __builtin_amdgcn_s_barrier();
        __builtin_amdgcn_sched_barrier(0);
        if (k0 + 64 * t < my_kend) compute(p, k0 + 64 * t);
        __builtin_amdgcn_sched_barrier(0);
        __builtin_amdgcn_s_barrier();
    }

    if (nseg == 1) {
        // ---- direct: y / l, pack pairs, store to [B,T,C] ----
#pragma unroll
        for (int m = 0; m < 2; m++) {
            const float inv = 1.f / lrun[m];
            const int t2 = qbase + m * 16 + lr;
#pragma unroll
            for (int n = 0; n < 4; n++)
#pragma unroll
                for (int rp = 0; rp < 2; rp++) {
                    u32 dw = cvt_pk_bf16(yacc[m][n][2 * rp] * inv, yacc[m][n][2 * rp + 1] * inv);
                    const int d = n * 16 + 4 * lg + 2 * rp;
                    *(u32*)&Yb[((size_t)(b * T_DIM + t2)) * C_DIM + h * 64 + d] = dw;
                }
        }
    } else {
        // ---- partial: unnormalized y (bf16) + (m,l) ----
        const int pidx = (c < 8)  ? (c - 4) * 2 + s
                       : (c < 12) ? 8 + (c - 8) * 3 + s
                                  : 20 + (c - 12) * 4 + s;
        u16* yp = Yp + ((size_t)(bh * NPSEG + pidx)) * 8192;   // [128 rows][64 d]
#pragma unroll
        for (int m = 0; m < 2; m++) {
            const int row = wv * 32 + m * 16 + lr;
#pragma unroll
            for (int n = 0; n < 4; n++)
#pragma unroll
                for (int rp = 0; rp < 2; rp++) {
                    u32 dw = cvt_pk_bf16(yacc[m][n][2 * rp], yacc[m][n][2 * rp + 1]);
                    const int d = n * 16 + 4 * lg + 2 * rp;
                    *(u32*)&yp[row * 64 + d] = dw;
                }
            if (lg == 0) {
                float2 ml; ml.x = mrun[m]; ml.y = lrun[m];
                Ml[((size_t)(bh * NPSEG + pidx)) * 128 + row] = ml;
            }
        }
    }
}

// ---------------- merge partial segments (chunks c>=4) ----------------
__global__ __launch_bounds__(256)
void attn_merge(const u16* __restrict__ Yp, const float2* __restrict__ Ml,
                u16* __restrict__ Yb) {
    const int bh = blockIdx.x;
    const int c  = 4 + blockIdx.y;
    const int b = bh / H_DIM, h = bh % H_DIM;
    const int nseg  = (c >> 2) + 1;             // 2..4
    const int pbase = (c < 8)  ? (c - 4) * 2
                    : (c < 12) ? 8 + (c - 8) * 3
                               : 20 + (c - 12) * 4;
    const int tid = threadIdx.x;
    const int row = tid >> 1, dh = tid & 1;     // 128 rows x 2 halves of 32 d

    float mv[4], lv[4];
#pragma unroll 4
    for (int s = 0; s < 4; s++) {
        if (s < nseg) {
            float2 t = Ml[((size_t)(bh * NPSEG + pbase + s)) * 128 + row];
            mv[s] = t.x; lv[s] = t.y;
        } else { mv[s] = -1e30f; lv[s] = 0.f; }
    }
    float mstar = fmaxf(fmaxf(mv[0], mv[1]), fmaxf(mv[2], mv[3]));
    float w[4], L = 0.f;
#pragma unroll 4
    for (int s = 0; s < 4; s++) { w[s] = exp2_hw(mv[s] - mstar); L += w[s] * lv[s]; }
    const float inv = 1.f / L;

    const size_t ybase = ((size_t)(bh * NPSEG + pbase)) * 8192 + row * 64 + dh * 32;
    u16* outp = Yb + ((size_t)(b * T_DIM + c * 128 + row)) * C_DIM + h * 64 + dh * 32;
#pragma unroll
    for (int v = 0; v < 4; v++) {
        float acc[8];
#pragma unroll
        for (int j = 0; j < 8; j++) acc[j] = 0.f;
#pragma unroll 4
        for (int s = 0; s < 4; s++) {
            if (s < nseg) {
                bf16x8 yv = *(const bf16x8*)&Yp[ybase + (size_t)s * 8192 + v * 8];
#pragma unroll
                for (int j = 0; j < 8; j++) acc[j] += w[s] * (float)yv[j];
            }
        }
#pragma unroll
        for (int jp = 0; jp < 4; jp++) {
            u32 dw = cvt_pk_bf16(acc[2 * jp] * inv, acc[2 * jp + 1] * inv);
            *(u32*)&outp[v * 8 + jp * 2] = dw;
        }
    }
}

// ---------------- launch ----------------
extern "C" void kernel_launch(void* const* d_in, const int* in_sizes, int n_in,
                              void* d_out, int out_size, void* d_ws, size_t ws_size,
                              hipStream_t stream) {
    const float* x      = (const float*)d_in[0];
    const float* W_attn = (const float*)d_in[1];
    const float* b_attn = (const float*)d_in[2];
    const float* W_proj = (const float*)d_in[3];
    const float* b_proj = (const float*)d_in[4];
    float* out = (float*)d_out;

    char* ws = (char*)d_ws;
    u16* xb  = (u16*)(ws);                       //  4096x768   bf16  (x)
    u16* WtA = (u16*)(ws + 6291456);             //  2304x768   bf16  (W_attn^T)
    u16* WtP = (u16*)(ws + 9830400);             //   768x768   bf16  (W_proj^T)
    u16* Qb  = (u16*)(ws + 11010048);            //  [B,H,T,D]  bf16  (pre-scaled by 0.125*log2e)
    u16* Kb  = (u16*)(ws + 17301504);            //  [B,H,T,D]  bf16
    u16* Vt  = (u16*)(ws + 23592960);            //  [B,H,D,T]  bf16
    u16* Yb  = (u16*)(ws + 29884416);            //  4096x768   bf16  (attn out)
    u16* Yp  = (u16*)(ws + 36175872);            //  [24][36][128][64] bf16 partial y (14.2 MB)
    float2* Ml = (float2*)(ws + 50331648);       //  [24][36][128] float2 (m,l)  (0.9 MB)

    // fused prep: convert x + transpose both weight matrices
    prep<<<5376, 256, 0, stream>>>(x, xb, W_attn, WtA, W_proj, WtP);
    // QKV GEMM: NJ=4 (128x128 tile, 4x4 acc/wave) -> grid 18x32
    gemm_bt<0, 4><<<dim3(2304 / 128, 4096 / 128), 256, 0, stream>>>(xb, WtA, b_attn, Qb, Kb, Vt, nullptr);
    // split-K LDS-staged attention: 24 bh x 40 segments, 4 waves each, XCD-aware placement
    attn_kernel<<<960, 256, 0, stream>>>(Qb, Kb, Vt, Yb, Yp, Ml);
    // merge partial segments (chunks c>=4)
    attn_merge<<<dim3(B_DIM * H_DIM, 12), 256, 0, stream>>>(Yp, Ml, Yb);
    // proj GEMM: NJ=2 (128x64 tile) keeps 384 blocks at skinny N
    gemm_bt<1, 2><<<dim3(768 / 64, 4096 / 128), 256, 0, stream>>>(Yb, WtP, b_proj, nullptr, nullptr, nullptr, out);
}

// Round 16
// 94.934 us; speedup vs baseline: 1.0627x; 1.0627x over previous
//
#include <hip/hip_runtime.h>

typedef unsigned short u16;
typedef unsigned int   u32;
typedef __bf16 bf16x8 __attribute__((ext_vector_type(8)));
typedef float  f32x4  __attribute__((ext_vector_type(4)));

#define B_DIM 2
#define T_DIM 2048
#define C_DIM 768
#define H_DIM 12
#define D_DIM 64
#define KD 768  // GEMM K dim (= C)

__device__ __forceinline__ u16 f2bf(float f) {
    union { float f; u32 u; } v; v.f = f;
    u32 r = v.u + 0x7FFFu + ((v.u >> 16) & 1u);   // RNE
    return (u16)(r >> 16);
}

__device__ __forceinline__ u32 cvt_pk_bf16(float lo, float hi) {
    u32 r;
    asm("v_cvt_pk_bf16_f32 %0, %1, %2" : "=v"(r) : "v"(lo), "v"(hi));
    return r;
}

__device__ __forceinline__ float exp2_hw(float x) {
    float r;
    asm("v_exp_f32 %0, %1" : "=v"(r) : "v"(x));
    return r;
}

__device__ __forceinline__ void load_lds16(const void* g, void* l) {
    __builtin_amdgcn_global_load_lds(
        (const __attribute__((address_space(1))) u32*)g,
        (__attribute__((address_space(3))) u32*)l,
        16, 0, 0);
}

// ---------------- fused prep: x fp32->bf16  +  W_attn / W_proj transpose+convert ----------------
__global__ __launch_bounds__(256)
void prep(const float* __restrict__ x,      u16* __restrict__ xb,
          const float* __restrict__ WA,     u16* __restrict__ WtA,
          const float* __restrict__ WP,     u16* __restrict__ WtP) {
    const int bid = blockIdx.x;
    const int tid = threadIdx.x;
    if (bid < 3072) {
        int i = bid * 256 + tid;
        float4 v = ((const float4*)x)[i];
        ushort4 o;
        o.x = f2bf(v.x); o.y = f2bf(v.y); o.z = f2bf(v.z); o.w = f2bf(v.w);
        ((ushort4*)xb)[i] = o;
        return;
    }
    __shared__ float tile[32][33];
    const float* W; u16* Wt; int N, idx;
    if (bid < 4800) { W = WA; Wt = WtA; N = 2304; idx = bid - 3072; }
    else            { W = WP; Wt = WtP; N = 768;  idx = bid - 4800; }
    const int tilesx = N / 32;
    const int bx = (idx % tilesx) * 32, by = (idx / tilesx) * 32;
    const int tx = tid & 31, ty = tid >> 5;
#pragma unroll
    for (int i = ty; i < 32; i += 8) tile[i][tx] = W[(size_t)(by + i) * N + bx + tx];
    __syncthreads();
#pragma unroll
    for (int i = ty; i < 32; i += 8) Wt[(size_t)(bx + i) * KD + by + tx] = f2bf(tile[tx][i]);
}

// ---------------- GEMM: A[M][768] bf16 @ Bt[N][768]^T, 128 x (NJ*32) tile, BK=64 ----------------
// T2 XOR-swizzle, double-buffered LDS with counted vmcnt(4+NJ), setprio on MFMA cluster.
// NJ=2 both GEMMs (R15 showed NJ=4 loses: 64KB LDS -> 2 blocks/CU at a 576-block grid).
template <int EPI, int NJ>
__global__ __launch_bounds__(256)
void gemm_bt(const u16* __restrict__ A, const u16* __restrict__ Bt,
             const float* __restrict__ bias,
             u16* __restrict__ Qb, u16* __restrict__ Kb, u16* __restrict__ Vt,
             float* __restrict__ Cout) {
    __shared__ u16 lA[2][128 * 64];
    __shared__ u16 lB[2][NJ * 32 * 64];
    const int tid  = threadIdx.x;
    const int lane = tid & 63, wv = tid >> 6;
    const int lr = lane & 15, lg = lane >> 4;
    const int wm = wv >> 1, wn = wv & 1;
    const int sw = (lr & 7) << 3;                         // read-side XOR (elem units)
    const int scol = (((lane & 7) ^ (lane >> 3)) << 3);   // pre-swizzled source col (elems)
    const int row0 = blockIdx.y * 128, col0 = blockIdx.x * (NJ * 32);

    const f32x4 Z4 = {0.f, 0.f, 0.f, 0.f};
    f32x4 acc[4][NJ];
#pragma unroll
    for (int i = 0; i < 4; i++)
#pragma unroll
        for (int j = 0; j < NJ; j++) acc[i][j] = Z4;

    auto stage = [&](int p, int kt) {
#pragma unroll
        for (int i = 0; i < 4; i++) {               // A: 16 chunks of 1KB
            int chunk = wv * 4 + i;
            int row = chunk * 8 + (lane >> 3);
            load_lds16(&A[(size_t)(row0 + row) * KD + kt * 64 + scol], &lA[p][chunk * 512]);
        }
#pragma unroll
        for (int i = 0; i < NJ; i++) {              // B: NJ*4 chunks of 1KB
            int chunk = wv * NJ + i;
            int row = chunk * 8 + (lane >> 3);
            load_lds16(&Bt[(size_t)(col0 + row) * KD + kt * 64 + scol], &lB[p][chunk * 512]);
        }
    };

    auto compute = [&](int p) {
#pragma unroll
        for (int kk = 0; kk < 2; kk++) {
            bf16x8 af[4], bfr[NJ];
#pragma unroll
            for (int i = 0; i < 4; i++)
                af[i] = *(const bf16x8*)&lA[p][(wm * 64 + i * 16 + lr) * 64 + ((kk * 32 + lg * 8) ^ sw)];
#pragma unroll
            for (int j = 0; j < NJ; j++)
                bfr[j] = *(const bf16x8*)&lB[p][(wn * (NJ * 16) + j * 16 + lr) * 64 + ((kk * 32 + lg * 8) ^ sw)];
            __builtin_amdgcn_s_setprio(1);
#pragma unroll
            for (int i = 0; i < 4; i++)
#pragma unroll
                for (int j = 0; j < NJ; j++)
                    acc[i][j] = __builtin_amdgcn_mfma_f32_16x16x32_bf16(af[i], bfr[j], acc[i][j], 0, 0, 0);
            __builtin_amdgcn_s_setprio(0);
        }
    };

    stage(0, 0);
    for (int kt = 0; kt < KD / 64; ++kt) {
        const int p = kt & 1;
        if (kt + 1 < KD / 64) {
            stage(p ^ 1, kt + 1);
            if constexpr (NJ == 4) asm volatile("s_waitcnt vmcnt(8)" ::: "memory");
            else                   asm volatile("s_waitcnt vmcnt(6)" ::: "memory");
        } else {
            asm volatile("s_waitcnt vmcnt(0)" ::: "memory");
        }
        __builtin_amdgcn_sched_barrier(0);
        __builtin_amdgcn_s_barrier();
        __builtin_amdgcn_sched_barrier(0);
        compute(p);
        __builtin_amdgcn_sched_barrier(0);
        __builtin_amdgcn_s_barrier();
    }

    if (EPI == 0) {
        const int b  = row0 >> 11;
        const int t0 = (row0 & 2047) + wm * 64;
        const float qscale = 0.125f * 1.44269504088896340736f;  // fold log2(e)
#pragma unroll
        for (int i = 0; i < 4; i++) {
#pragma unroll
            for (int j = 0; j < NJ; j++) {
                const int n   = col0 + wn * (NJ * 16) + j * 16 + lr;
                const int seg = n / 768;
                const int nn  = n - seg * 768;
                const int h   = nn >> 6;
                const int d   = nn & 63;
                const float bv = bias[n];
                const int tb  = t0 + i * 16 + lg * 4;
                if (seg == 2) {
                    // Vt rows contiguous in t: pack 4 consecutive t into one 8B store
                    u32 w0 = cvt_pk_bf16(acc[i][j][0] + bv, acc[i][j][1] + bv);
                    u32 w1 = cvt_pk_bf16(acc[i][j][2] + bv, acc[i][j][3] + bv);
                    uint2 dw; dw.x = w0; dw.y = w1;
                    *(uint2*)&Vt[((size_t)(b * H_DIM + h) * D_DIM + d) * T_DIM + tb] = dw;
                } else if (seg == 0) {
#pragma unroll
                    for (int r = 0; r < 4; r++)
                        Qb[((size_t)(b * H_DIM + h) * T_DIM + tb + r) * D_DIM + d] =
                            f2bf((acc[i][j][r] + bv) * qscale);
                } else {
#pragma unroll
                    for (int r = 0; r < 4; r++)
                        Kb[((size_t)(b * H_DIM + h) * T_DIM + tb + r) * D_DIM + d] =
                            f2bf(acc[i][j][r] + bv);
                }
            }
        }
    } else {
#pragma unroll
        for (int i = 0; i < 4; i++)
#pragma unroll
            for (int j = 0; j < NJ; j++) {
                const int n  = col0 + wn * (NJ * 16) + j * 16 + lr;
                const float bv = bias[n];
#pragma unroll
                for (int r = 0; r < 4; r++) {
                    const int m = row0 + wm * 64 + i * 16 + lg * 4 + r;
                    Cout[(size_t)m * 768 + n] = acc[i][j][r] + bv;
                }
            }
    }
}

// ---------------- causal flash attention: 8-wave paired-chunk blocks + split-K ----------------
// Work item = (bh, chunk-PAIR cp of 2x128 q-rows, <=512-key segment s).  Chunks 2cp and 2cp+1
// share every K/V segment (same nseg) -> one 8-wave block: waves 0-3 own chunk 2cp, waves 4-7
// own chunk 2cp+1; K/V staged ONCE (staging instrs/wave and staged L2 traffic both halve).
// 20 items/bh (LPT table: 16 full 8-tile segments first, 4 short last), 480 blocks x 512 thr.
// Per-wave my_kend mask handles the shorter chunk's causal boundary (same as before).
// c<=3 (nseg==1): direct write.  Else bf16 partial y + (m,l) -> attn_merge (unchanged).
union VFrag  { struct { ushort4 lo, hi; } s; bf16x8 v; };
union PFrag  { u32 w[4]; bf16x8 v; };
union QU     { f32x4 f; bf16x8 b; };

#define NPSEG 36   // partial-segment slots per bh (chunks c>=4)

__global__ __launch_bounds__(512)
void attn_kernel(const u16* __restrict__ Qb, const u16* __restrict__ Kb,
                 const u16* __restrict__ Vt, u16* __restrict__ Yb,
                 u16* __restrict__ Yp, float2* __restrict__ Ml) {
    __shared__ u16 ldsK[2][64 * 64];
    __shared__ u16 ldsV[2][64 * 64];

    const int i    = blockIdx.x;
    const int bh   = (i & 7) + 8 * ((i >> 3) % 3);   // XCD-aware: 3 heads per XCD
    const int rank = (i >> 3) / 3;                   // 0..19, LPT order (long segments first)
    // (cp,s) table encoded as cp*4+s: 16 full-length items then 4 short ones
    const unsigned char CPS[20] = {28,29,30,31, 24,25,26, 20,21,22, 16,17, 12,13, 8, 4, 0, 9, 18, 27};
    const int e  = CPS[rank];
    const int cp = e >> 2, s = e & 3;

    const int b = bh / H_DIM, h = bh % H_DIM;
    const int tid  = threadIdx.x;
    const int lane = tid & 63, wv = tid >> 6;        // wv 0..7
    const int lr = lane & 15, lg = lane >> 4;
    const int sw = (lr & 7) << 3;                    // read-side XOR swizzle (elem units)
    const int c  = 2 * cp + (wv >> 2);               // this wave's q-chunk (32-row granule owner below)
    const int nseg = (c >> 2) + 1;                   // equal for both chunks of the pair
    const int qbase = c * 128 + (wv & 3) * 32;
    const int my_kend = qbase + 32;
    const int k0 = s * 512;
    const int k1 = min(512 * (s + 1), (cp + 1) * 256 * 1);   // larger chunk's kend
    const int nt = (k1 - k0) >> 6;                   // 4 or 8 tiles

    const u16* Qp = Qb + (size_t)bh * T_DIM * D_DIM;
    const u16* Kp = Kb + (size_t)bh * T_DIM * D_DIM;
    const u16* Vp = Vt + (size_t)bh * D_DIM * T_DIM;

    // Q fragments (B-operand): col = lr = q-within-16, contraction d = lg*8+j
    QU qf[2][2];
#pragma unroll
    for (int m = 0; m < 2; m++)
#pragma unroll
        for (int dh = 0; dh < 2; dh++)
            qf[m][dh].f = *(const f32x4*)&Qp[(size_t)(qbase + m * 16 + lr) * 64 + dh * 32 + lg * 8];
    asm volatile("" :: "v"(qf[0][0].f), "v"(qf[0][1].f), "v"(qf[1][0].f), "v"(qf[1][1].f));

    const f32x4 Z4 = {0.f, 0.f, 0.f, 0.f};
    f32x4 yacc[2][4];
    float mrun[2] = {-1e30f, -1e30f};
    float lrun[2] = {0.f, 0.f};
#pragma unroll
    for (int m = 0; m < 2; m++)
#pragma unroll
        for (int n = 0; n < 4; n++) yacc[m][n] = Z4;

    // staging geometry: wave w stages rows [8w, 8w+8) of K and V (ONE gload each)
    const int srow = wv * 8 + (lane >> 3);
    const int scol = (((lane & 7) ^ (lane >> 3)) << 3);   // pre-swizzled source col (elems)

    auto stage = [&](int p, int kc) {
        load_lds16(Kp + (size_t)(kc + srow) * 64 + scol, &ldsK[p][(wv * 8) * 64]);
        load_lds16(Vp + (size_t)srow * T_DIM + kc + scol, &ldsV[p][(wv * 8) * 64]);
    };

    auto compute = [&](int p, int kc) {
        // ---- K frags from LDS (swizzled) ----
        QU k0f[4], k1f[4];
#pragma unroll
        for (int kf = 0; kf < 4; kf++) {
            const u16* krow = &ldsK[p][(kf * 16 + lr) * 64];
            k0f[kf].f = *(const f32x4*)&krow[(lg * 8) ^ sw];
            k1f[kf].f = *(const f32x4*)&krow[(32 + lg * 8) ^ sw];
        }
        // ---- S^T = K @ Q^T ----
        f32x4 S[2][4];
#pragma unroll
        for (int m = 0; m < 2; m++)
#pragma unroll
            for (int kf = 0; kf < 4; kf++) S[m][kf] = Z4;
        __builtin_amdgcn_s_setprio(1);
#pragma unroll
        for (int kf = 0; kf < 4; kf++)
#pragma unroll
            for (int m = 0; m < 2; m++) {
                S[m][kf] = __builtin_amdgcn_mfma_f32_16x16x32_bf16(k0f[kf].b, qf[m][0].b, S[m][kf], 0, 0, 0);
                S[m][kf] = __builtin_amdgcn_mfma_f32_16x16x32_bf16(k1f[kf].b, qf[m][1].b, S[m][kf], 0, 0, 0);
            }
        __builtin_amdgcn_s_setprio(0);

        // ---- causal mask (diagonal-crossing tiles only) ----
        if (kc + 63 > qbase) {
#pragma unroll
            for (int m = 0; m < 2; m++) {
                const int q = qbase + m * 16 + lr;
#pragma unroll
                for (int kf = 0; kf < 4; kf++)
#pragma unroll
                    for (int r = 0; r < 4; r++) {
                        const int k = kc + kf * 16 + 4 * lg + r;
                        if (k > q) S[m][kf][r] = -1e30f;
                    }
            }
        }

        // ---- online softmax with defer-max ----
        PFrag pf[2][2];
#pragma unroll
        for (int m = 0; m < 2; m++) {
            float mx = -1e30f;
#pragma unroll
            for (int kf = 0; kf < 4; kf++) {
                float a = fmaxf(S[m][kf][0], S[m][kf][1]);
                float cm = fmaxf(S[m][kf][2], S[m][kf][3]);
                mx = fmaxf(mx, fmaxf(a, cm));
            }
            mx = fmaxf(mx, __shfl_xor(mx, 16));
            mx = fmaxf(mx, __shfl_xor(mx, 32));
            if (!__all(mx <= mrun[m] + 8.0f)) {
                float mnew = fmaxf(mrun[m], mx);
                float sfr  = exp2_hw(mrun[m] - mnew);
                mrun[m] = mnew;
                lrun[m] *= sfr;
#pragma unroll
                for (int n = 0; n < 4; n++)
#pragma unroll
                    for (int r = 0; r < 4; r++) yacc[m][n][r] *= sfr;
            }
            float sum = 0.f;
#pragma unroll
            for (int kf = 0; kf < 4; kf++)
#pragma unroll
                for (int r = 0; r < 4; r++) {
                    float pb = exp2_hw(S[m][kf][r] - mrun[m]);
                    S[m][kf][r] = pb;
                    sum += pb;
                }
            sum += __shfl_xor(sum, 16);
            sum += __shfl_xor(sum, 32);
            lrun[m] += sum;
#pragma unroll
            for (int sv = 0; sv < 2; sv++) {
                pf[m][sv].w[0] = cvt_pk_bf16(S[m][2 * sv][0],     S[m][2 * sv][1]);
                pf[m][sv].w[1] = cvt_pk_bf16(S[m][2 * sv][2],     S[m][2 * sv][3]);
                pf[m][sv].w[2] = cvt_pk_bf16(S[m][2 * sv + 1][0], S[m][2 * sv + 1][1]);
                pf[m][sv].w[3] = cvt_pk_bf16(S[m][2 * sv + 1][2], S[m][2 * sv + 1][3]);
            }
        }

        // ---- y^T += V^T @ P^T  (V frags from LDS, swizzled; own-register P slots) ----
        __builtin_amdgcn_s_setprio(1);
#pragma unroll
        for (int sv = 0; sv < 2; sv++) {
            VFrag av[4];
#pragma unroll
            for (int n = 0; n < 4; n++) {
                const u16* vrow = &ldsV[p][(n * 16 + lr) * 64];
                av[n].s.lo = *(const ushort4*)&vrow[(sv * 32 + 4 * lg) ^ sw];
                av[n].s.hi = *(const ushort4*)&vrow[(sv * 32 + 16 + 4 * lg) ^ sw];
            }
#pragma unroll
            for (int n = 0; n < 4; n++)
#pragma unroll
                for (int m = 0; m < 2; m++)
                    yacc[m][n] = __builtin_amdgcn_mfma_f32_16x16x32_bf16(av[n].v, pf[m][sv].v, yacc[m][n], 0, 0, 0);
        }
        __builtin_amdgcn_s_setprio(0);
    };

    // ---- pipelined tile loop: stage(t+1) in flight across the barrier (counted vmcnt) ----
    stage(0, k0);
    for (int t = 0; t < nt; ++t) {
        const int p = t & 1;
        if (t + 1 < nt) {
            stage(p ^ 1, k0 + 64 * (t + 1));
            asm volatile("s_waitcnt vmcnt(2)" ::: "memory");   // tile t landed; t+1's 2 loads in flight
        } else {
            asm volatile("s_waitcnt vmcnt(0)" ::: "memory");
        }
        __builtin_amdgcn_sched_barrier(0);
        __builtin_amdgcn_s_barrier();
        __builtin_amdgcn_sched_barrier(0);
        if (k0 + 64 * t < my_kend) compute(p, k0 + 64 * t);
        __builtin_amdgcn_sched_barrier(0);
        __builtin_amdgcn_s_barrier();
    }

    if (nseg == 1) {
        // ---- direct: y / l, pack pairs, store to [B,T,C] ----
#pragma unroll
        for (int m = 0; m < 2; m++) {
            const float inv = 1.f / lrun[m];
            const int t2 = qbase + m * 16 + lr;
#pragma unroll
            for (int n = 0; n < 4; n++)
#pragma unroll
                for (int rp = 0; rp < 2; rp++) {
                    u32 dw = cvt_pk_bf16(yacc[m][n][2 * rp] * inv, yacc[m][n][2 * rp + 1] * inv);
                    const int d = n * 16 + 4 * lg + 2 * rp;
                    *(u32*)&Yb[((size_t)(b * T_DIM + t2)) * C_DIM + h * 64 + d] = dw;
                }
        }
    } else {
        // ---- partial: unnormalized y (bf16) + (m,l) ----
        const int pidx = (c < 8)  ? (c - 4) * 2 + s
                       : (c < 12) ? 8 + (c - 8) * 3 + s
                                  : 20 + (c - 12) * 4 + s;
        u16* yp = Yp + ((size_t)(bh * NPSEG + pidx)) * 8192;   // [128 rows][64 d]
#pragma unroll
        for (int m = 0; m < 2; m++) {
            const int row = (wv & 3) * 32 + m * 16 + lr;
#pragma unroll
            for (int n = 0; n < 4; n++)
#pragma unroll
                for (int rp = 0; rp < 2; rp++) {
                    u32 dw = cvt_pk_bf16(yacc[m][n][2 * rp], yacc[m][n][2 * rp + 1]);
                    const int d = n * 16 + 4 * lg + 2 * rp;
                    *(u32*)&yp[row * 64 + d] = dw;
                }
            if (lg == 0) {
                float2 ml; ml.x = mrun[m]; ml.y = lrun[m];
                Ml[((size_t)(bh * NPSEG + pidx)) * 128 + row] = ml;
            }
        }
    }
}

// ---------------- merge partial segments (chunks c>=4) ----------------
__global__ __launch_bounds__(256)
void attn_merge(const u16* __restrict__ Yp, const float2* __restrict__ Ml,
                u16* __restrict__ Yb) {
    const int bh = blockIdx.x;
    const int c  = 4 + blockIdx.y;
    const int b = bh / H_DIM, h = bh % H_DIM;
    const int nseg  = (c >> 2) + 1;             // 2..4
    const int pbase = (c < 8)  ? (c - 4) * 2
                    : (c < 12) ? 8 + (c - 8) * 3
                               : 20 + (c - 12) * 4;
    const int tid = threadIdx.x;
    const int row = tid >> 1, dh = tid & 1;     // 128 rows x 2 halves of 32 d

    float mv[4], lv[4];
#pragma unroll 4
    for (int s = 0; s < 4; s++) {
        if (s < nseg) {
            float2 t = Ml[((size_t)(bh * NPSEG + pbase + s)) * 128 + row];
            mv[s] = t.x; lv[s] = t.y;
        } else { mv[s] = -1e30f; lv[s] = 0.f; }
    }
    float mstar = fmaxf(fmaxf(mv[0], mv[1]), fmaxf(mv[2], mv[3]));
    float w[4], L = 0.f;
#pragma unroll 4
    for (int s = 0; s < 4; s++) { w[s] = exp2_hw(mv[s] - mstar); L += w[s] * lv[s]; }
    const float inv = 1.f / L;

    const size_t ybase = ((size_t)(bh * NPSEG + pbase)) * 8192 + row * 64 + dh * 32;
    u16* outp = Yb + ((size_t)(b * T_DIM + c * 128 + row)) * C_DIM + h * 64 + dh * 32;
#pragma unroll
    for (int v = 0; v < 4; v++) {
        float acc[8];
#pragma unroll
        for (int j = 0; j < 8; j++) acc[j] = 0.f;
#pragma unroll 4
        for (int s = 0; s < 4; s++) {
            if (s < nseg) {
                bf16x8 yv = *(const bf16x8*)&Yp[ybase + (size_t)s * 8192 + v * 8];
#pragma unroll
                for (int j = 0; j < 8; j++) acc[j] += w[s] * (float)yv[j];
            }
        }
#pragma unroll
        for (int jp = 0; jp < 4; jp++) {
            u32 dw = cvt_pk_bf16(acc[2 * jp] * inv, acc[2 * jp + 1] * inv);
            *(u32*)&outp[v * 8 + jp * 2] = dw;
        }
    }
}

// ---------------- launch ----------------
extern "C" void kernel_launch(void* const* d_in, const int* in_sizes, int n_in,
                              void* d_out, int out_size, void* d_ws, size_t ws_size,
                              hipStream_t stream) {
    const float* x      = (const float*)d_in[0];
    const float* W_attn = (const float*)d_in[1];
    const float* b_attn = (const float*)d_in[2];
    const float* W_proj = (const float*)d_in[3];
    const float* b_proj = (const float*)d_in[4];
    float* out = (float*)d_out;

    char* ws = (char*)d_ws;
    u16* xb  = (u16*)(ws);                       //  4096x768   bf16  (x)
    u16* WtA = (u16*)(ws + 6291456);             //  2304x768   bf16  (W_attn^T)
    u16* WtP = (u16*)(ws + 9830400);             //   768x768   bf16  (W_proj^T)
    u16* Qb  = (u16*)(ws + 11010048);            //  [B,H,T,D]  bf16  (pre-scaled by 0.125*log2e)
    u16* Kb  = (u16*)(ws + 17301504);            //  [B,H,T,D]  bf16
    u16* Vt  = (u16*)(ws + 23592960);            //  [B,H,D,T]  bf16
    u16* Yb  = (u16*)(ws + 29884416);            //  4096x768   bf16  (attn out)
    u16* Yp  = (u16*)(ws + 36175872);            //  [24][36][128][64] bf16 partial y (14.2 MB)
    float2* Ml = (float2*)(ws + 50331648);       //  [24][36][128] float2 (m,l)  (0.9 MB)

    // fused prep: convert x + transpose both weight matrices
    prep<<<5376, 256, 0, stream>>>(x, xb, W_attn, WtA, W_proj, WtP);
    // QKV GEMM: NJ=2 (measured-best: 1152 blocks, 4.5/CU)
    gemm_bt<0, 2><<<dim3(2304 / 64, 4096 / 128), 256, 0, stream>>>(xb, WtA, b_attn, Qb, Kb, Vt, nullptr);
    // paired-chunk split-K attention: 24 bh x 20 items, 8 waves each, shared K/V staging
    attn_kernel<<<480, 512, 0, stream>>>(Qb, Kb, Vt, Yb, Yp, Ml);
    // merge partial segments (chunks c>=4)
    attn_merge<<<dim3(B_DIM * H_DIM, 12), 256, 0, stream>>>(Yp, Ml, Yb);
    // proj GEMM: NJ=2
    gemm_bt<1, 2><<<dim3(768 / 64, 4096 / 128), 256, 0, stream>>>(Yb, WtP, b_proj, nullptr, nullptr, nullptr, out);
}

// Round 17
// 92.389 us; speedup vs baseline: 1.0920x; 1.0275x over previous
//
#include <hip/hip_runtime.h>

typedef unsigned short u16;
typedef unsigned int   u32;
typedef __bf16 bf16x8 __attribute__((ext_vector_type(8)));
typedef float  f32x4  __attribute__((ext_vector_type(4)));

#define B_DIM 2
#define T_DIM 2048
#define C_DIM 768
#define H_DIM 12
#define D_DIM 64
#define KD 768  // GEMM K dim (= C)

__device__ __forceinline__ u16 f2bf(float f) {
    union { float f; u32 u; } v; v.f = f;
    u32 r = v.u + 0x7FFFu + ((v.u >> 16) & 1u);   // RNE
    return (u16)(r >> 16);
}

__device__ __forceinline__ u32 cvt_pk_bf16(float lo, float hi) {
    u32 r;
    asm("v_cvt_pk_bf16_f32 %0, %1, %2" : "=v"(r) : "v"(lo), "v"(hi));
    return r;
}

__device__ __forceinline__ float exp2_hw(float x) {
    float r;
    asm("v_exp_f32 %0, %1" : "=v"(r) : "v"(x));
    return r;
}

__device__ __forceinline__ void load_lds16(const void* g, void* l) {
    __builtin_amdgcn_global_load_lds(
        (const __attribute__((address_space(1))) u32*)g,
        (__attribute__((address_space(3))) u32*)l,
        16, 0, 0);
}

// ---------------- fused prep: x fp32->bf16  +  W_attn / W_proj transpose+convert ----------------
__global__ __launch_bounds__(256)
void prep(const float* __restrict__ x,      u16* __restrict__ xb,
          const float* __restrict__ WA,     u16* __restrict__ WtA,
          const float* __restrict__ WP,     u16* __restrict__ WtP) {
    const int bid = blockIdx.x;
    const int tid = threadIdx.x;
    if (bid < 3072) {
        int i = bid * 256 + tid;
        float4 v = ((const float4*)x)[i];
        ushort4 o;
        o.x = f2bf(v.x); o.y = f2bf(v.y); o.z = f2bf(v.z); o.w = f2bf(v.w);
        ((ushort4*)xb)[i] = o;
        return;
    }
    __shared__ float tile[32][33];
    const float* W; u16* Wt; int N, idx;
    if (bid < 4800) { W = WA; Wt = WtA; N = 2304; idx = bid - 3072; }
    else            { W = WP; Wt = WtP; N = 768;  idx = bid - 4800; }
    const int tilesx = N / 32;
    const int bx = (idx % tilesx) * 32, by = (idx / tilesx) * 32;
    const int tx = tid & 31, ty = tid >> 5;
#pragma unroll
    for (int i = ty; i < 32; i += 8) tile[i][tx] = W[(size_t)(by + i) * N + bx + tx];
    __syncthreads();
#pragma unroll
    for (int i = ty; i < 32; i += 8) Wt[(size_t)(bx + i) * KD + by + tx] = f2bf(tile[tx][i]);
}

// ---------------- GEMM: A[M][768] bf16 @ Bt[N][768]^T, 128 x (NJ*32) tile, BK=64 ----------------
// T2 XOR-swizzle, double-buffered LDS with counted vmcnt(4+NJ), setprio on MFMA cluster.
// T1 (R17): XCD-aware bijective block swizzle — consecutive linear block ids land on ONE XCD,
// so each XCD works on ~NBX/8 contiguous row-bands: A-panels + full B fit its 4MB L2.
template <int EPI, int NJ>
__global__ __launch_bounds__(256)
void gemm_bt(const u16* __restrict__ A, const u16* __restrict__ Bt,
             const float* __restrict__ bias,
             u16* __restrict__ Qb, u16* __restrict__ Kb, u16* __restrict__ Vt,
             float* __restrict__ Cout, int nbx) {
    __shared__ u16 lA[2][128 * 64];
    __shared__ u16 lB[2][NJ * 32 * 64];
    const int tid  = threadIdx.x;
    const int lane = tid & 63, wv = tid >> 6;
    const int lr = lane & 15, lg = lane >> 4;
    const int wm = wv >> 1, wn = wv & 1;
    const int sw = (lr & 7) << 3;                         // read-side XOR (elem units)
    const int scol = (((lane & 7) ^ (lane >> 3)) << 3);   // pre-swizzled source col (elems)

    // T1: bijective XCD swizzle (grid divisible by 8). orig id i -> xcd = i%8 gets chunk i/8.
    const int nwg  = nbx * (int)gridDim.y;
    const int cpx  = nwg >> 3;                            // chunk per XCD (nwg % 8 == 0)
    const int iorg = (int)blockIdx.x + (int)blockIdx.y * nbx;
    const int iswz = (iorg & 7) * cpx + (iorg >> 3);
    const int bx   = iswz % nbx, by = iswz / nbx;
    const int row0 = by * 128, col0 = bx * (NJ * 32);

    const f32x4 Z4 = {0.f, 0.f, 0.f, 0.f};
    f32x4 acc[4][NJ];
#pragma unroll
    for (int i = 0; i < 4; i++)
#pragma unroll
        for (int j = 0; j < NJ; j++) acc[i][j] = Z4;

    auto stage = [&](int p, int kt) {
#pragma unroll
        for (int i = 0; i < 4; i++) {               // A: 16 chunks of 1KB
            int chunk = wv * 4 + i;
            int row = chunk * 8 + (lane >> 3);
            load_lds16(&A[(size_t)(row0 + row) * KD + kt * 64 + scol], &lA[p][chunk * 512]);
        }
#pragma unroll
        for (int i = 0; i < NJ; i++) {              // B: NJ*4 chunks of 1KB
            int chunk = wv * NJ + i;
            int row = chunk * 8 + (lane >> 3);
            load_lds16(&Bt[(size_t)(col0 + row) * KD + kt * 64 + scol], &lB[p][chunk * 512]);
        }
    };

    auto compute = [&](int p) {
#pragma unroll
        for (int kk = 0; kk < 2; kk++) {
            bf16x8 af[4], bfr[NJ];
#pragma unroll
            for (int i = 0; i < 4; i++)
                af[i] = *(const bf16x8*)&lA[p][(wm * 64 + i * 16 + lr) * 64 + ((kk * 32 + lg * 8) ^ sw)];
#pragma unroll
            for (int j = 0; j < NJ; j++)
                bfr[j] = *(const bf16x8*)&lB[p][(wn * (NJ * 16) + j * 16 + lr) * 64 + ((kk * 32 + lg * 8) ^ sw)];
            __builtin_amdgcn_s_setprio(1);
#pragma unroll
            for (int i = 0; i < 4; i++)
#pragma unroll
                for (int j = 0; j < NJ; j++)
                    acc[i][j] = __builtin_amdgcn_mfma_f32_16x16x32_bf16(af[i], bfr[j], acc[i][j], 0, 0, 0);
            __builtin_amdgcn_s_setprio(0);
        }
    };

    stage(0, 0);
    for (int kt = 0; kt < KD / 64; ++kt) {
        const int p = kt & 1;
        if (kt + 1 < KD / 64) {
            stage(p ^ 1, kt + 1);
            if constexpr (NJ == 4) asm volatile("s_waitcnt vmcnt(8)" ::: "memory");
            else                   asm volatile("s_waitcnt vmcnt(6)" ::: "memory");
        } else {
            asm volatile("s_waitcnt vmcnt(0)" ::: "memory");
        }
        __builtin_amdgcn_sched_barrier(0);
        __builtin_amdgcn_s_barrier();
        __builtin_amdgcn_sched_barrier(0);
        compute(p);
        __builtin_amdgcn_sched_barrier(0);
        __builtin_amdgcn_s_barrier();
    }

    if (EPI == 0) {
        const int b  = row0 >> 11;
        const int t0 = (row0 & 2047) + wm * 64;
        const float qscale = 0.125f * 1.44269504088896340736f;  // fold log2(e)
#pragma unroll
        for (int i = 0; i < 4; i++) {
#pragma unroll
            for (int j = 0; j < NJ; j++) {
                const int n   = col0 + wn * (NJ * 16) + j * 16 + lr;
                const int seg = n / 768;
                const int nn  = n - seg * 768;
                const int h   = nn >> 6;
                const int d   = nn & 63;
                const float bv = bias[n];
                const int tb  = t0 + i * 16 + lg * 4;
                if (seg == 2) {
                    // Vt rows contiguous in t: pack 4 consecutive t into one 8B store
                    u32 w0 = cvt_pk_bf16(acc[i][j][0] + bv, acc[i][j][1] + bv);
                    u32 w1 = cvt_pk_bf16(acc[i][j][2] + bv, acc[i][j][3] + bv);
                    uint2 dw; dw.x = w0; dw.y = w1;
                    *(uint2*)&Vt[((size_t)(b * H_DIM + h) * D_DIM + d) * T_DIM + tb] = dw;
                } else if (seg == 0) {
#pragma unroll
                    for (int r = 0; r < 4; r++)
                        Qb[((size_t)(b * H_DIM + h) * T_DIM + tb + r) * D_DIM + d] =
                            f2bf((acc[i][j][r] + bv) * qscale);
                } else {
#pragma unroll
                    for (int r = 0; r < 4; r++)
                        Kb[((size_t)(b * H_DIM + h) * T_DIM + tb + r) * D_DIM + d] =
                            f2bf(acc[i][j][r] + bv);
                }
            }
        }
    } else {
#pragma unroll
        for (int i = 0; i < 4; i++)
#pragma unroll
            for (int j = 0; j < NJ; j++) {
                const int n  = col0 + wn * (NJ * 16) + j * 16 + lr;
                const float bv = bias[n];
#pragma unroll
                for (int r = 0; r < 4; r++) {
                    const int m = row0 + wm * 64 + i * 16 + lg * 4 + r;
                    Cout[(size_t)m * 768 + n] = acc[i][j][r] + bv;
                }
            }
    }
}

// ---------------- causal flash attention: 4-wave LDS-staged blocks + split-K (R12-exact) ----------------
// Work item = (bh, 128-row q-chunk c, <=512-key segment s).  40 items/bh, 960 blocks.
// 2-buffer LDS, 1-deep prefetch, counted vmcnt(4), XOR swizzle, in-register softmax/PV.
union VFrag  { struct { ushort4 lo, hi; } s; bf16x8 v; };
union PFrag  { u32 w[4]; bf16x8 v; };
union QU     { f32x4 f; bf16x8 b; };

#define NPSEG 36   // partial-segment slots per bh (chunks c>=4)

__global__ __launch_bounds__(256)
void attn_kernel(const u16* __restrict__ Qb, const u16* __restrict__ Kb,
                 const u16* __restrict__ Vt, u16* __restrict__ Yb,
                 u16* __restrict__ Yp, float2* __restrict__ Ml) {
    __shared__ u16 ldsK[2][64 * 64];
    __shared__ u16 ldsV[2][64 * 64];

    const int i    = blockIdx.x;
    const int bh   = (i & 7) + 8 * ((i >> 3) % 3);
    const int rank = (i >> 3) / 3;              // 0..39
    int c, s;
    if (rank < 4)       { c = 4 + rank;              s = 0; }
    else if (rank < 12) { c = 8 + ((rank - 4) >> 1); s = (rank - 4) & 1; }
    else if (rank < 24) { c = 12 + (rank - 12) / 3;  s = (rank - 12) % 3; }
    else { int j = rank - 24; c = 4 * (j & 3) + (3 - (j >> 2)); s = c >> 2; }
    const int nseg = (c >> 2) + 1;

    const int b = bh / H_DIM, h = bh % H_DIM;
    const int tid  = threadIdx.x;
    const int lane = tid & 63, wv = tid >> 6;
    const int lr = lane & 15, lg = lane >> 4;
    const int sw = (lr & 7) << 3;               // read-side XOR swizzle (elem units)
    const int q0 = c * 128;
    const int qbase = q0 + wv * 32;
    const int my_kend = qbase + 32;
    const int k0 = s * 512;
    const int k1 = min(512 * (s + 1), q0 + 128);
    const int nt = (k1 - k0) >> 6;              // 2..8 tiles

    const u16* Qp = Qb + (size_t)bh * T_DIM * D_DIM;
    const u16* Kp = Kb + (size_t)bh * T_DIM * D_DIM;
    const u16* Vp = Vt + (size_t)bh * D_DIM * T_DIM;

    // Q fragments (B-operand): col = lr = q-within-16, contraction d = lg*8+j
    QU qf[2][2];
#pragma unroll
    for (int m = 0; m < 2; m++)
#pragma unroll
        for (int dh = 0; dh < 2; dh++)
            qf[m][dh].f = *(const f32x4*)&Qp[(size_t)(qbase + m * 16 + lr) * 64 + dh * 32 + lg * 8];
    asm volatile("" :: "v"(qf[0][0].f), "v"(qf[0][1].f), "v"(qf[1][0].f), "v"(qf[1][1].f));

    const f32x4 Z4 = {0.f, 0.f, 0.f, 0.f};
    f32x4 yacc[2][4];
    float mrun[2] = {-1e30f, -1e30f};
    float lrun[2] = {0.f, 0.f};
#pragma unroll
    for (int m = 0; m < 2; m++)
#pragma unroll
        for (int n = 0; n < 4; n++) yacc[m][n] = Z4;

    // staging geometry: wave w stages rows [16w,16w+16) of K and V (2 instrs each of 8 rows)
    const int srow = wv * 16 + (lane >> 3);
    const int scol = (((lane & 7) ^ (lane >> 3)) << 3);   // pre-swizzled source col (elems)

    auto stage = [&](int p, int kc) {
#pragma unroll
        for (int j = 0; j < 2; j++) {
            const int r = srow + j * 8;
            load_lds16(Kp + (size_t)(kc + r) * 64 + scol, &ldsK[p][(wv * 16 + j * 8) * 64]);
            load_lds16(Vp + (size_t)r * T_DIM + kc + scol, &ldsV[p][(wv * 16 + j * 8) * 64]);
        }
    };

    auto compute = [&](int p, int kc) {
        // ---- K frags from LDS (swizzled) ----
        QU k0f[4], k1f[4];
#pragma unroll
        for (int kf = 0; kf < 4; kf++) {
            const u16* krow = &ldsK[p][(kf * 16 + lr) * 64];
            k0f[kf].f = *(const f32x4*)&krow[(lg * 8) ^ sw];
            k1f[kf].f = *(const f32x4*)&krow[(32 + lg * 8) ^ sw];
        }
        // ---- S^T = K @ Q^T ----
        f32x4 S[2][4];
#pragma unroll
        for (int m = 0; m < 2; m++)
#pragma unroll
            for (int kf = 0; kf < 4; kf++) S[m][kf] = Z4;
        __builtin_amdgcn_s_setprio(1);
#pragma unroll
        for (int kf = 0; kf < 4; kf++)
#pragma unroll
            for (int m = 0; m < 2; m++) {
                S[m][kf] = __builtin_amdgcn_mfma_f32_16x16x32_bf16(k0f[kf].b, qf[m][0].b, S[m][kf], 0, 0, 0);
                S[m][kf] = __builtin_amdgcn_mfma_f32_16x16x32_bf16(k1f[kf].b, qf[m][1].b, S[m][kf], 0, 0, 0);
            }
        __builtin_amdgcn_s_setprio(0);

        // ---- causal mask (diagonal-crossing tiles only) ----
        if (kc + 63 > qbase) {
#pragma unroll
            for (int m = 0; m < 2; m++) {
                const int q = qbase + m * 16 + lr;
#pragma unroll
                for (int kf = 0; kf < 4; kf++)
#pragma unroll
                    for (int r = 0; r < 4; r++) {
                        const int k = kc + kf * 16 + 4 * lg + r;
                        if (k > q) S[m][kf][r] = -1e30f;
                    }
            }
        }

        // ---- online softmax with defer-max ----
        PFrag pf[2][2];
#pragma unroll
        for (int m = 0; m < 2; m++) {
            float mx = -1e30f;
#pragma unroll
            for (int kf = 0; kf < 4; kf++) {
                float a = fmaxf(S[m][kf][0], S[m][kf][1]);
                float cm = fmaxf(S[m][kf][2], S[m][kf][3]);
                mx = fmaxf(mx, fmaxf(a, cm));
            }
            mx = fmaxf(mx, __shfl_xor(mx, 16));
            mx = fmaxf(mx, __shfl_xor(mx, 32));
            if (!__all(mx <= mrun[m] + 8.0f)) {
                float mnew = fmaxf(mrun[m], mx);
                float sfr  = exp2_hw(mrun[m] - mnew);
                mrun[m] = mnew;
                lrun[m] *= sfr;
#pragma unroll
                for (int n = 0; n < 4; n++)
#pragma unroll
                    for (int r = 0; r < 4; r++) yacc[m][n][r] *= sfr;
            }
            float sum = 0.f;
#pragma unroll
            for (int kf = 0; kf < 4; kf++)
#pragma unroll
                for (int r = 0; r < 4; r++) {
                    float pb = exp2_hw(S[m][kf][r] - mrun[m]);
                    S[m][kf][r] = pb;
                    sum += pb;
                }
            sum += __shfl_xor(sum, 16);
            sum += __shfl_xor(sum, 32);
            lrun[m] += sum;
#pragma unroll
            for (int sv = 0; sv < 2; sv++) {
                pf[m][sv].w[0] = cvt_pk_bf16(S[m][2 * sv][0],     S[m][2 * sv][1]);
                pf[m][sv].w[1] = cvt_pk_bf16(S[m][2 * sv][2],     S[m][2 * sv][3]);
                pf[m][sv].w[2] = cvt_pk_bf16(S[m][2 * sv + 1][0], S[m][2 * sv + 1][1]);
                pf[m][sv].w[3] = cvt_pk_bf16(S[m][2 * sv + 1][2], S[m][2 * sv + 1][3]);
            }
        }

        // ---- y^T += V^T @ P^T  (V frags from LDS, swizzled; own-register P slots) ----
        __builtin_amdgcn_s_setprio(1);
#pragma unroll
        for (int sv = 0; sv < 2; sv++) {
            VFrag av[4];
#pragma unroll
            for (int n = 0; n < 4; n++) {
                const u16* vrow = &ldsV[p][(n * 16 + lr) * 64];
                av[n].s.lo = *(const ushort4*)&vrow[(sv * 32 + 4 * lg) ^ sw];
                av[n].s.hi = *(const ushort4*)&vrow[(sv * 32 + 16 + 4 * lg) ^ sw];
            }
#pragma unroll
            for (int n = 0; n < 4; n++)
#pragma unroll
                for (int m = 0; m < 2; m++)
                    yacc[m][n] = __builtin_amdgcn_mfma_f32_16x16x32_bf16(av[n].v, pf[m][sv].v, yacc[m][n], 0, 0, 0);
        }
        __builtin_amdgcn_s_setprio(0);
    };

    // ---- pipelined tile loop: stage(t+1) in flight across the barrier (counted vmcnt) ----
    stage(0, k0);
    for (int t = 0; t < nt; ++t) {
        const int p = t & 1;
        if (t + 1 < nt) {
            stage(p ^ 1, k0 + 64 * (t + 1));
            asm volatile("s_waitcnt vmcnt(4)" ::: "memory");   // tile t landed; t+1 in flight
        } else {
            asm volatile("s_waitcnt vmcnt(0)" ::: "memory");
        }
        __builtin_amdgcn_sched_barrier(0);
        __builtin_amdgcn_s_barrier();
        __builtin_amdgcn_sched_barrier(0);
        if (k0 + 64 * t < my_kend) compute(p, k0 + 64 * t);
        __builtin_amdgcn_sched_barrier(0);
        __builtin_amdgcn_s_barrier();
    }

    if (nseg == 1) {
        // ---- direct: y / l, pack pairs, store to [B,T,C] ----
#pragma unroll
        for (int m = 0; m < 2; m++) {
            const float inv = 1.f / lrun[m];
            const int t2 = qbase + m * 16 + lr;
#pragma unroll
            for (int n = 0; n < 4; n++)
#pragma unroll
                for (int rp = 0; rp < 2; rp++) {
                    u32 dw = cvt_pk_bf16(yacc[m][n][2 * rp] * inv, yacc[m][n][2 * rp + 1] * inv);
                    const int d = n * 16 + 4 * lg + 2 * rp;
                    *(u32*)&Yb[((size_t)(b * T_DIM + t2)) * C_DIM + h * 64 + d] = dw;
                }
        }
    } else {
        // ---- partial: unnormalized y (bf16) + (m,l) ----
        const int pidx = (c < 8)  ? (c - 4) * 2 + s
                       : (c < 12) ? 8 + (c - 8) * 3 + s
                                  : 20 + (c - 12) * 4 + s;
        u16* yp = Yp + ((size_t)(bh * NPSEG + pidx)) * 8192;   // [128 rows][64 d]
#pragma unroll
        for (int m = 0; m < 2; m++) {
            const int row = wv * 32 + m * 16 + lr;
#pragma unroll
            for (int n = 0; n < 4; n++)
#pragma unroll
                for (int rp = 0; rp < 2; rp++) {
                    u32 dw = cvt_pk_bf16(yacc[m][n][2 * rp], yacc[m][n][2 * rp + 1]);
                    const int d = n * 16 + 4 * lg + 2 * rp;
                    *(u32*)&yp[row * 64 + d] = dw;
                }
            if (lg == 0) {
                float2 ml; ml.x = mrun[m]; ml.y = lrun[m];
                Ml[((size_t)(bh * NPSEG + pidx)) * 128 + row] = ml;
            }
        }
    }
}

// ---------------- merge partial segments (chunks c>=4) ----------------
__global__ __launch_bounds__(256)
void attn_merge(const u16* __restrict__ Yp, const float2* __restrict__ Ml,
                u16* __restrict__ Yb) {
    const int bh = blockIdx.x;
    const int c  = 4 + blockIdx.y;
    const int b = bh / H_DIM, h = bh % H_DIM;
    const int nseg  = (c >> 2) + 1;             // 2..4
    const int pbase = (c < 8)  ? (c - 4) * 2
                    : (c < 12) ? 8 + (c - 8) * 3
                               : 20 + (c - 12) * 4;
    const int tid = threadIdx.x;
    const int row = tid >> 1, dh = tid & 1;     // 128 rows x 2 halves of 32 d

    float mv[4], lv[4];
#pragma unroll 4
    for (int s = 0; s < 4; s++) {
        if (s < nseg) {
            float2 t = Ml[((size_t)(bh * NPSEG + pbase + s)) * 128 + row];
            mv[s] = t.x; lv[s] = t.y;
        } else { mv[s] = -1e30f; lv[s] = 0.f; }
    }
    float mstar = fmaxf(fmaxf(mv[0], mv[1]), fmaxf(mv[2], mv[3]));
    float w[4], L = 0.f;
#pragma unroll 4
    for (int s = 0; s < 4; s++) { w[s] = exp2_hw(mv[s] - mstar); L += w[s] * lv[s]; }
    const float inv = 1.f / L;

    const size_t ybase = ((size_t)(bh * NPSEG + pbase)) * 8192 + row * 64 + dh * 32;
    u16* outp = Yb + ((size_t)(b * T_DIM + c * 128 + row)) * C_DIM + h * 64 + dh * 32;
#pragma unroll
    for (int v = 0; v < 4; v++) {
        float acc[8];
#pragma unroll
        for (int j = 0; j < 8; j++) acc[j] = 0.f;
#pragma unroll 4
        for (int s = 0; s < 4; s++) {
            if (s < nseg) {
                bf16x8 yv = *(const bf16x8*)&Yp[ybase + (size_t)s * 8192 + v * 8];
#pragma unroll
                for (int j = 0; j < 8; j++) acc[j] += w[s] * (float)yv[j];
            }
        }
#pragma unroll
        for (int jp = 0; jp < 4; jp++) {
            u32 dw = cvt_pk_bf16(acc[2 * jp] * inv, acc[2 * jp + 1] * inv);
            *(u32*)&outp[v * 8 + jp * 2] = dw;
        }
    }
}

// ---------------- launch ----------------
extern "C" void kernel_launch(void* const* d_in, const int* in_sizes, int n_in,
                              void* d_out, int out_size, void* d_ws, size_t ws_size,
                              hipStream_t stream) {
    const float* x      = (const float*)d_in[0];
    const float* W_attn = (const float*)d_in[1];
    const float* b_attn = (const float*)d_in[2];
    const float* W_proj = (const float*)d_in[3];
    const float* b_proj = (const float*)d_in[4];
    float* out = (float*)d_out;

    char* ws = (char*)d_ws;
    u16* xb  = (u16*)(ws);                       //  4096x768   bf16  (x)
    u16* WtA = (u16*)(ws + 6291456);             //  2304x768   bf16  (W_attn^T)
    u16* WtP = (u16*)(ws + 9830400);             //   768x768   bf16  (W_proj^T)
    u16* Qb  = (u16*)(ws + 11010048);            //  [B,H,T,D]  bf16  (pre-scaled by 0.125*log2e)
    u16* Kb  = (u16*)(ws + 17301504);            //  [B,H,T,D]  bf16
    u16* Vt  = (u16*)(ws + 23592960);            //  [B,H,D,T]  bf16
    u16* Yb  = (u16*)(ws + 29884416);            //  4096x768   bf16  (attn out)
    u16* Yp  = (u16*)(ws + 36175872);            //  [24][36][128][64] bf16 partial y (14.2 MB)
    float2* Ml = (float2*)(ws + 50331648);       //  [24][36][128] float2 (m,l)  (0.9 MB)

    // fused prep: convert x + transpose both weight matrices
    prep<<<5376, 256, 0, stream>>>(x, xb, W_attn, WtA, W_proj, WtP);
    // QKV GEMM: NJ=2, T1 XCD swizzle (1152 blocks % 8 == 0)
    gemm_bt<0, 2><<<dim3(2304 / 64, 4096 / 128), 256, 0, stream>>>(xb, WtA, b_attn, Qb, Kb, Vt, nullptr, 2304 / 64);
    // split-K LDS-staged attention: 24 bh x 40 segments, 4 waves each, XCD-aware placement
    attn_kernel<<<960, 256, 0, stream>>>(Qb, Kb, Vt, Yb, Yp, Ml);
    // merge partial segments (chunks c>=4)
    attn_merge<<<dim3(B_DIM * H_DIM, 12), 256, 0, stream>>>(Yp, Ml, Yb);
    // proj GEMM: NJ=2, T1 XCD swizzle (384 blocks % 8 == 0)
    gemm_bt<1, 2><<<dim3(768 / 64, 4096 / 128), 256, 0, stream>>>(Yb, WtP, b_proj, nullptr, nullptr, nullptr, out, 768 / 64);
}